// Round 1
// baseline (7253.246 us; speedup 1.0000x reference)
//
#include <hip/hip_runtime.h>
#include <hip/hip_bf16.h>
#include <cstddef>

// GraphSAGE (3x SAGEConv mean-aggr + FC) on MI355X.
// Round 0: correct fp32 baseline.
//   - deg/invdeg precompute (atomicAdd counting)
//   - per layer: memset agg -> edge-parallel float4 gather + atomicAdd scatter
//                -> fused GEMM: relu( (agg*invdeg) @ Wl + bl + x @ Wr )
//   - final FC (K=256, N=9) with W in LDS
// Workspace layout (floats): deg | invdeg | agg(M*128) | h1(M*128) | h2(M*128) | h3(M*256)

#define N_IN 64
#define N_HID 128
#define N_OUT 9

// ---------------- degree ----------------
__global__ void deg_kernel(const int* __restrict__ dst, float* __restrict__ deg, int E) {
    int t = blockIdx.x * 256 + threadIdx.x;
    if (t < E) atomicAdd(&deg[dst[t]], 1.0f);
}

__global__ void invdeg_kernel(const float* __restrict__ deg, float* __restrict__ invdeg, int M) {
    int t = blockIdx.x * 256 + threadIdx.x;
    if (t < M) invdeg[t] = 1.0f / fmaxf(deg[t], 1.0f);
}

// ---------------- scatter-add aggregation ----------------
// one thread per (edge, 4-float chunk); shift = log2(dim/4)
__global__ void scatter_kernel(const float* __restrict__ feat, const int* __restrict__ src,
                               const int* __restrict__ dst, float* __restrict__ agg,
                               int E, int shift) {
    int t = blockIdx.x * 256 + threadIdx.x;
    int total = E << shift;
    if (t >= total) return;
    int e = t >> shift;
    int c = (t & ((1 << shift) - 1)) << 2;   // float offset within row
    int dim = 4 << shift;
    int s = src[e];
    int d = dst[e];
    const float4 v = *(const float4*)(feat + (size_t)s * dim + c);
    float* p = agg + (size_t)d * dim + c;
    atomicAdd(p + 0, v.x);
    atomicAdd(p + 1, v.y);
    atomicAdd(p + 2, v.z);
    atomicAdd(p + 3, v.w);
}

// ---------------- fused SAGE GEMM ----------------
// out[m,n] = act( sum_k agg[m,k]*invdeg[m]*Wl[k,n] + sum_k Ax[m,k]*Wr[k,n] + bias[n] )
// BM=BN=64, BK=16, 256 threads, 4x4 micro-tile per thread.
#define BM 64
#define BN 64
#define BK 16
#define LDT 68   // LDS row stride (floats): 68*4=272 bytes, 16B-aligned rows

__global__ __launch_bounds__(256) void sage_gemm_kernel(
    const float* __restrict__ Aagg, const float* __restrict__ invdeg,
    const float* __restrict__ Ax,
    const float* __restrict__ Wl, const float* __restrict__ Wr,
    const float* __restrict__ bias, float* __restrict__ outp,
    int M, int K, int N, int do_relu)
{
    __shared__ float As[BK][LDT];
    __shared__ float Bs[BK][LDT];
    const int tid = threadIdx.x;
    const int bm = blockIdx.y * BM;
    const int bn = blockIdx.x * BN;
    const int tx = tid & 15;          // -> n
    const int ty = tid >> 4;          // -> m

    float acc[4][4];
#pragma unroll
    for (int i = 0; i < 4; ++i)
#pragma unroll
        for (int j = 0; j < 4; ++j) acc[i][j] = 0.0f;

    const int am = tid >> 2;          // 0..63 (row within tile)
    const int ak = (tid & 3) * 4;     // 0,4,8,12 (k offset)
    const int gm = bm + am;
    const bool mval = gm < M;
    const int wk = tid >> 4;          // 0..15
    const int wn = (tid & 15) * 4;    // 0..60

    for (int phase = 0; phase < 2; ++phase) {
        const float* __restrict__ A = phase ? Ax : Aagg;
        const float* __restrict__ W = phase ? Wr : Wl;
        const float scale = phase ? 1.0f : (mval ? invdeg[gm] : 0.0f);
        for (int k0 = 0; k0 < K; k0 += BK) {
            float4 av = make_float4(0.f, 0.f, 0.f, 0.f);
            if (mval) av = *(const float4*)(A + (size_t)gm * K + k0 + ak);
            const float4 wv = *(const float4*)(W + (size_t)(k0 + wk) * N + bn + wn);
            __syncthreads();   // previous iteration's LDS reads done
            As[ak + 0][am] = av.x * scale;
            As[ak + 1][am] = av.y * scale;
            As[ak + 2][am] = av.z * scale;
            As[ak + 3][am] = av.w * scale;
            *(float4*)&Bs[wk][wn] = wv;
            __syncthreads();
#pragma unroll
            for (int kk = 0; kk < BK; ++kk) {
                const float4 a = *(const float4*)&As[kk][ty * 4];
                const float4 b = *(const float4*)&Bs[kk][tx * 4];
                acc[0][0] += a.x * b.x; acc[0][1] += a.x * b.y; acc[0][2] += a.x * b.z; acc[0][3] += a.x * b.w;
                acc[1][0] += a.y * b.x; acc[1][1] += a.y * b.y; acc[1][2] += a.y * b.z; acc[1][3] += a.y * b.w;
                acc[2][0] += a.z * b.x; acc[2][1] += a.z * b.y; acc[2][2] += a.z * b.z; acc[2][3] += a.z * b.w;
                acc[3][0] += a.w * b.x; acc[3][1] += a.w * b.y; acc[3][2] += a.w * b.z; acc[3][3] += a.w * b.w;
            }
        }
    }

#pragma unroll
    for (int i = 0; i < 4; ++i) {
        const int row = bm + ty * 4 + i;
        if (row < M) {
            const int col = bn + tx * 4;
            float4 r;
            r.x = acc[i][0] + bias[col + 0];
            r.y = acc[i][1] + bias[col + 1];
            r.z = acc[i][2] + bias[col + 2];
            r.w = acc[i][3] + bias[col + 3];
            if (do_relu) {
                r.x = fmaxf(r.x, 0.f); r.y = fmaxf(r.y, 0.f);
                r.z = fmaxf(r.z, 0.f); r.w = fmaxf(r.w, 0.f);
            }
            *(float4*)(outp + (size_t)row * N + col) = r;
        }
    }
}

// ---------------- final FC: out[i,j] = h[i,:]@W[:,j] + b[j], K=256, N=9 ----------------
__global__ __launch_bounds__(256) void fc_kernel(const float* __restrict__ h,
                                                 const float* __restrict__ W,
                                                 const float* __restrict__ b,
                                                 float* __restrict__ outp, int M) {
    __shared__ float Ws[256 * N_OUT];
    __shared__ float bs[N_OUT];
    for (int i = threadIdx.x; i < 256 * N_OUT; i += 256) Ws[i] = W[i];
    if (threadIdx.x < N_OUT) bs[threadIdx.x] = b[threadIdx.x];
    __syncthreads();
    const int t = blockIdx.x * 256 + threadIdx.x;
    if (t >= M * N_OUT) return;
    const int i = t / N_OUT;
    const int j = t - i * N_OUT;
    const float* __restrict__ row = h + (size_t)i * 256;
    float s = bs[j];
#pragma unroll 8
    for (int k = 0; k < 256; ++k) s += row[k] * Ws[k * N_OUT + j];
    outp[t] = s;
}

extern "C" void kernel_launch(void* const* d_in, const int* in_sizes, int n_in,
                              void* d_out, int out_size, void* d_ws, size_t ws_size,
                              hipStream_t stream) {
    const float* x   = (const float*)d_in[0];
    const int*   ei  = (const int*)d_in[1];
    const float* Wl1 = (const float*)d_in[2];
    const float* bl1 = (const float*)d_in[3];
    const float* Wr1 = (const float*)d_in[4];
    const float* Wl2 = (const float*)d_in[5];
    const float* bl2 = (const float*)d_in[6];
    const float* Wr2 = (const float*)d_in[7];
    const float* Wl3 = (const float*)d_in[8];
    const float* bl3 = (const float*)d_in[9];
    const float* Wr3 = (const float*)d_in[10];
    const float* Wfc = (const float*)d_in[11];
    const float* bfc = (const float*)d_in[12];
    float* outp = (float*)d_out;

    const int M = in_sizes[0] / N_IN;        // 100000 nodes
    const int E = in_sizes[1] / 2;           // 1600000 edges
    const int* src = ei;
    const int* dst = ei + E;

    // workspace carve-up (floats)
    float* ws = (float*)d_ws;
    size_t o = 0;
    float* deg    = ws + o; o += 102400;                 // M rounded up
    float* invdeg = ws + o; o += 102400;
    float* agg    = ws + o; o += (size_t)M * N_HID;      // max-width accumulator
    float* h1     = ws + o; o += (size_t)M * N_HID;
    float* h2     = ws + o; o += (size_t)M * N_HID;
    float* h3     = ws + o; o += (size_t)M * 2 * N_HID;
    (void)ws_size; (void)n_in; (void)out_size;

    const int blk = 256;

    // degree + inverse degree
    hipMemsetAsync(deg, 0, (size_t)M * sizeof(float), stream);
    deg_kernel<<<(E + blk - 1) / blk, blk, 0, stream>>>(dst, deg, E);
    invdeg_kernel<<<(M + blk - 1) / blk, blk, 0, stream>>>(deg, invdeg, M);

    const int gy = (M + BM - 1) / BM;

    // ---- layer 1: in 64 -> out 128 ----
    hipMemsetAsync(agg, 0, (size_t)M * N_IN * sizeof(float), stream);
    {
        int shift = 4;                        // 64/4 chunks
        int total = E << shift;
        scatter_kernel<<<(total + blk - 1) / blk, blk, 0, stream>>>(x, src, dst, agg, E, shift);
        sage_gemm_kernel<<<dim3(N_HID / BN, gy), blk, 0, stream>>>(
            agg, invdeg, x, Wl1, Wr1, bl1, h1, M, N_IN, N_HID, 1);
    }

    // ---- layer 2: 128 -> 128 ----
    hipMemsetAsync(agg, 0, (size_t)M * N_HID * sizeof(float), stream);
    {
        int shift = 5;                        // 128/4 chunks
        int total = E << shift;
        scatter_kernel<<<(total + blk - 1) / blk, blk, 0, stream>>>(h1, src, dst, agg, E, shift);
        sage_gemm_kernel<<<dim3(N_HID / BN, gy), blk, 0, stream>>>(
            agg, invdeg, h1, Wl2, Wr2, bl2, h2, M, N_HID, N_HID, 1);
    }

    // ---- layer 3: 128 -> 256 ----
    hipMemsetAsync(agg, 0, (size_t)M * N_HID * sizeof(float), stream);
    {
        int shift = 5;
        int total = E << shift;
        scatter_kernel<<<(total + blk - 1) / blk, blk, 0, stream>>>(h2, src, dst, agg, E, shift);
        sage_gemm_kernel<<<dim3(2 * N_HID / BN, gy), blk, 0, stream>>>(
            agg, invdeg, h2, Wl3, Wr3, bl3, h3, M, N_HID, 2 * N_HID, 1);
    }

    // ---- final FC: 256 -> 9 ----
    {
        int total = M * N_OUT;
        fc_kernel<<<(total + blk - 1) / blk, blk, 0, stream>>>(h3, Wfc, bfc, outp, M);
    }
}

// Round 2
// 959.802 us; speedup vs baseline: 7.5570x; 7.5570x over previous
//
#include <hip/hip_runtime.h>
#include <hip/hip_bf16.h>
#include <cstddef>

// GraphSAGE (3x SAGEConv mean-aggr + FC) on MI355X.
// Round 1: replace atomic scatter-add aggregation (3.2 GB HBM writes/layer)
// with CSR-by-dst build + register-accumulating gather (51 MB writes/layer).
//   - CSR build per call: int degree histogram -> 3-kernel prefix scan ->
//     atomic-cursor fill of col[] (src ids grouped by dst)
//   - per layer: gather_mean kernel (slot of dim/4 threads per node, float4
//     register accumulate, invdeg folded into the single write)
//   - fused GEMM: relu( mean @ Wl + bl + x @ Wr )  (no scaling needed now)
//   - final FC (K=256, N=9) with W in LDS
// col[] aliases the head of h3: last col read (gather3) precedes first h3
// write (gemm3) in stream order.

#define N_IN 64
#define N_HID 128
#define N_OUT 9

// ---------------- degree (int) ----------------
__global__ void deg_int_kernel(const int* __restrict__ dst, int* __restrict__ degi, int E) {
    int t = blockIdx.x * 256 + threadIdx.x;
    if (t < E) atomicAdd(&degi[dst[t]], 1);
}

// ---------------- prefix scan (3 kernels) ----------------
__global__ __launch_bounds__(256) void block_sum_kernel(const int* __restrict__ degi,
                                                        int* __restrict__ partial, int M) {
    __shared__ int sm[256];
    int i = blockIdx.x * 256 + threadIdx.x;
    sm[threadIdx.x] = (i < M) ? degi[i] : 0;
    __syncthreads();
    for (int s = 128; s > 0; s >>= 1) {
        if (threadIdx.x < s) sm[threadIdx.x] += sm[threadIdx.x + s];
        __syncthreads();
    }
    if (threadIdx.x == 0) partial[blockIdx.x] = sm[0];
}

__global__ void top_scan_kernel(int* __restrict__ partial, int nb) {
    if (blockIdx.x == 0 && threadIdx.x == 0) {
        int run = 0;
        for (int b = 0; b < nb; ++b) { int v = partial[b]; partial[b] = run; run += v; }
    }
}

__global__ __launch_bounds__(256) void apply_scan_kernel(
    const int* __restrict__ degi, const int* __restrict__ partial,
    int* __restrict__ row_start, int* __restrict__ cursor,
    float* __restrict__ invdeg, int M)
{
    __shared__ int sm[256];
    int i = blockIdx.x * 256 + threadIdx.x;
    int d = (i < M) ? degi[i] : 0;
    sm[threadIdx.x] = d;
    __syncthreads();
    for (int off = 1; off < 256; off <<= 1) {
        int v = (threadIdx.x >= off) ? sm[threadIdx.x - off] : 0;
        __syncthreads();
        sm[threadIdx.x] += v;
        __syncthreads();
    }
    if (i < M) {
        int rs = partial[blockIdx.x] + sm[threadIdx.x] - d;  // exclusive prefix
        row_start[i] = rs;
        cursor[i] = rs;
        invdeg[i] = 1.0f / fmaxf((float)d, 1.0f);
    }
}

// ---------------- CSR fill ----------------
__global__ void fill_kernel(const int* __restrict__ src, const int* __restrict__ dst,
                            int* __restrict__ cursor, int* __restrict__ col, int E) {
    int e = blockIdx.x * 256 + threadIdx.x;
    if (e < E) {
        int p = atomicAdd(&cursor[dst[e]], 1);
        col[p] = src[e];
    }
}

// ---------------- gather-mean aggregation ----------------
// CH = float4 chunks per feature row (16 for dim 64, 32 for dim 128).
// One slot of CH threads per node; each thread owns one float4 chunk.
template <int CH>
__global__ __launch_bounds__(256) void gather_mean_kernel(
    const float* __restrict__ feat, const int* __restrict__ col,
    const int* __restrict__ row_start, const int* __restrict__ degi,
    const float* __restrict__ invdeg, float* __restrict__ agg, int M)
{
    constexpr int SLOTS = 256 / CH;
    constexpr int DIM = CH * 4;
    const int tid = threadIdx.x;
    const int slot = tid / CH;
    const int ch = tid % CH;
    const int node = blockIdx.x * SLOTS + slot;
    if (node >= M) return;
    const int beg = row_start[node];
    const int cnt = degi[node];
    float4 acc = make_float4(0.f, 0.f, 0.f, 0.f);
    int j = 0;
    for (; j + 1 < cnt; j += 2) {
        const int s0 = col[beg + j];
        const int s1 = col[beg + j + 1];
        const float4 v0 = *(const float4*)(feat + (size_t)s0 * DIM + ch * 4);
        const float4 v1 = *(const float4*)(feat + (size_t)s1 * DIM + ch * 4);
        acc.x += v0.x; acc.y += v0.y; acc.z += v0.z; acc.w += v0.w;
        acc.x += v1.x; acc.y += v1.y; acc.z += v1.z; acc.w += v1.w;
    }
    if (j < cnt) {
        const int s0 = col[beg + j];
        const float4 v0 = *(const float4*)(feat + (size_t)s0 * DIM + ch * 4);
        acc.x += v0.x; acc.y += v0.y; acc.z += v0.z; acc.w += v0.w;
    }
    const float sc = invdeg[node];
    float4 r = make_float4(acc.x * sc, acc.y * sc, acc.z * sc, acc.w * sc);
    *(float4*)(agg + (size_t)node * DIM + ch * 4) = r;
}

// ---------------- fused SAGE GEMM ----------------
// out[m,n] = relu( sum_k mean[m,k]*Wl[k,n] + sum_k Ax[m,k]*Wr[k,n] + bias[n] )
#define BM 64
#define BN 64
#define BK 16
#define LDT 68   // LDS row stride (floats)

__global__ __launch_bounds__(256) void sage_gemm_kernel(
    const float* __restrict__ Amean, const float* __restrict__ Ax,
    const float* __restrict__ Wl, const float* __restrict__ Wr,
    const float* __restrict__ bias, float* __restrict__ outp,
    int M, int K, int N, int do_relu)
{
    __shared__ float As[BK][LDT];
    __shared__ float Bs[BK][LDT];
    const int tid = threadIdx.x;
    const int bm = blockIdx.y * BM;
    const int bn = blockIdx.x * BN;
    const int tx = tid & 15;          // -> n
    const int ty = tid >> 4;          // -> m

    float acc[4][4];
#pragma unroll
    for (int i = 0; i < 4; ++i)
#pragma unroll
        for (int j = 0; j < 4; ++j) acc[i][j] = 0.0f;

    const int am = tid >> 2;          // 0..63 (row within tile)
    const int ak = (tid & 3) * 4;     // 0,4,8,12 (k offset)
    const int gm = bm + am;
    const bool mval = gm < M;
    const int wk = tid >> 4;          // 0..15
    const int wn = (tid & 15) * 4;    // 0..60

    for (int phase = 0; phase < 2; ++phase) {
        const float* __restrict__ A = phase ? Ax : Amean;
        const float* __restrict__ W = phase ? Wr : Wl;
        for (int k0 = 0; k0 < K; k0 += BK) {
            float4 av = make_float4(0.f, 0.f, 0.f, 0.f);
            if (mval) av = *(const float4*)(A + (size_t)gm * K + k0 + ak);
            const float4 wv = *(const float4*)(W + (size_t)(k0 + wk) * N + bn + wn);
            __syncthreads();   // previous iteration's LDS reads done
            As[ak + 0][am] = av.x;
            As[ak + 1][am] = av.y;
            As[ak + 2][am] = av.z;
            As[ak + 3][am] = av.w;
            *(float4*)&Bs[wk][wn] = wv;
            __syncthreads();
#pragma unroll
            for (int kk = 0; kk < BK; ++kk) {
                const float4 a = *(const float4*)&As[kk][ty * 4];
                const float4 b = *(const float4*)&Bs[kk][tx * 4];
                acc[0][0] += a.x * b.x; acc[0][1] += a.x * b.y; acc[0][2] += a.x * b.z; acc[0][3] += a.x * b.w;
                acc[1][0] += a.y * b.x; acc[1][1] += a.y * b.y; acc[1][2] += a.y * b.z; acc[1][3] += a.y * b.w;
                acc[2][0] += a.z * b.x; acc[2][1] += a.z * b.y; acc[2][2] += a.z * b.z; acc[2][3] += a.z * b.w;
                acc[3][0] += a.w * b.x; acc[3][1] += a.w * b.y; acc[3][2] += a.w * b.z; acc[3][3] += a.w * b.w;
            }
        }
    }

#pragma unroll
    for (int i = 0; i < 4; ++i) {
        const int row = bm + ty * 4 + i;
        if (row < M) {
            const int col4 = bn + tx * 4;
            float4 r;
            r.x = acc[i][0] + bias[col4 + 0];
            r.y = acc[i][1] + bias[col4 + 1];
            r.z = acc[i][2] + bias[col4 + 2];
            r.w = acc[i][3] + bias[col4 + 3];
            if (do_relu) {
                r.x = fmaxf(r.x, 0.f); r.y = fmaxf(r.y, 0.f);
                r.z = fmaxf(r.z, 0.f); r.w = fmaxf(r.w, 0.f);
            }
            *(float4*)(outp + (size_t)row * N + col4) = r;
        }
    }
}

// ---------------- final FC: out[i,j] = h[i,:]@W[:,j] + b[j], K=256, N=9 ----------------
__global__ __launch_bounds__(256) void fc_kernel(const float* __restrict__ h,
                                                 const float* __restrict__ W,
                                                 const float* __restrict__ b,
                                                 float* __restrict__ outp, int M) {
    __shared__ float Ws[256 * N_OUT];
    __shared__ float bs[N_OUT];
    for (int i = threadIdx.x; i < 256 * N_OUT; i += 256) Ws[i] = W[i];
    if (threadIdx.x < N_OUT) bs[threadIdx.x] = b[threadIdx.x];
    __syncthreads();
    const int t = blockIdx.x * 256 + threadIdx.x;
    if (t >= M * N_OUT) return;
    const int i = t / N_OUT;
    const int j = t - i * N_OUT;
    const float* __restrict__ row = h + (size_t)i * 256;
    float s = bs[j];
#pragma unroll 8
    for (int k = 0; k < 256; ++k) s += row[k] * Ws[k * N_OUT + j];
    outp[t] = s;
}

extern "C" void kernel_launch(void* const* d_in, const int* in_sizes, int n_in,
                              void* d_out, int out_size, void* d_ws, size_t ws_size,
                              hipStream_t stream) {
    const float* x   = (const float*)d_in[0];
    const int*   ei  = (const int*)d_in[1];
    const float* Wl1 = (const float*)d_in[2];
    const float* bl1 = (const float*)d_in[3];
    const float* Wr1 = (const float*)d_in[4];
    const float* Wl2 = (const float*)d_in[5];
    const float* bl2 = (const float*)d_in[6];
    const float* Wr2 = (const float*)d_in[7];
    const float* Wl3 = (const float*)d_in[8];
    const float* bl3 = (const float*)d_in[9];
    const float* Wr3 = (const float*)d_in[10];
    const float* Wfc = (const float*)d_in[11];
    const float* bfc = (const float*)d_in[12];
    float* outp = (float*)d_out;

    const int M = in_sizes[0] / N_IN;        // 100000 nodes
    const int E = in_sizes[1] / 2;           // 1600000 edges
    const int* src = ei;
    const int* dst = ei + E;
    const int NB = (M + 255) / 256;          // scan blocks

    // workspace carve-up (4-byte units); col aliases head of h3
    const size_t Mpad = 100352;              // M rounded to 1024
    char* wsb = (char*)d_ws;
    int*   degi      = (int*)wsb;                       wsb += Mpad * 4;
    int*   row_start = (int*)wsb;                       wsb += Mpad * 4;
    int*   cursor    = (int*)wsb;                       wsb += Mpad * 4;
    int*   partial   = (int*)wsb;                       wsb += 1024 * 4;
    float* invdeg    = (float*)wsb;                     wsb += Mpad * 4;
    float* agg       = (float*)wsb;                     wsb += (size_t)M * N_HID * 4;
    float* h1        = (float*)wsb;                     wsb += (size_t)M * N_HID * 4;
    float* h2        = (float*)wsb;                     wsb += (size_t)M * N_HID * 4;
    float* h3        = (float*)wsb;                     wsb += (size_t)M * 2 * N_HID * 4;
    int*   col       = (int*)h3;             // E ints = 6.4 MB inside h3 (102.4 MB)
    (void)ws_size; (void)n_in; (void)out_size;

    const int blk = 256;

    // ---- CSR build (by dst) + invdeg ----
    hipMemsetAsync(degi, 0, (size_t)M * sizeof(int), stream);
    deg_int_kernel<<<(E + blk - 1) / blk, blk, 0, stream>>>(dst, degi, E);
    block_sum_kernel<<<NB, blk, 0, stream>>>(degi, partial, M);
    top_scan_kernel<<<1, 64, 0, stream>>>(partial, NB);
    apply_scan_kernel<<<NB, blk, 0, stream>>>(degi, partial, row_start, cursor, invdeg, M);
    fill_kernel<<<(E + blk - 1) / blk, blk, 0, stream>>>(src, dst, cursor, col, E);

    const int gy = (M + BM - 1) / BM;

    // ---- layer 1: in 64 -> out 128 ----
    {
        constexpr int CH = N_IN / 4;         // 16
        const int slots = 256 / CH;
        gather_mean_kernel<CH><<<(M + slots - 1) / slots, blk, 0, stream>>>(
            x, col, row_start, degi, invdeg, agg, M);
        sage_gemm_kernel<<<dim3(N_HID / BN, gy), blk, 0, stream>>>(
            agg, x, Wl1, Wr1, bl1, h1, M, N_IN, N_HID, 1);
    }

    // ---- layer 2: 128 -> 128 ----
    {
        constexpr int CH = N_HID / 4;        // 32
        const int slots = 256 / CH;
        gather_mean_kernel<CH><<<(M + slots - 1) / slots, blk, 0, stream>>>(
            h1, col, row_start, degi, invdeg, agg, M);
        sage_gemm_kernel<<<dim3(N_HID / BN, gy), blk, 0, stream>>>(
            agg, h1, Wl2, Wr2, bl2, h2, M, N_HID, N_HID, 1);
    }

    // ---- layer 3: 128 -> 256 (gemm3 overwrites col region of h3 after last use) ----
    {
        constexpr int CH = N_HID / 4;        // 32
        const int slots = 256 / CH;
        gather_mean_kernel<CH><<<(M + slots - 1) / slots, blk, 0, stream>>>(
            h2, col, row_start, degi, invdeg, agg, M);
        sage_gemm_kernel<<<dim3(2 * N_HID / BN, gy), blk, 0, stream>>>(
            agg, h2, Wl3, Wr3, bl3, h3, M, N_HID, 2 * N_HID, 1);
    }

    // ---- final FC: 256 -> 9 ----
    {
        int total = M * N_OUT;
        fc_kernel<<<(total + blk - 1) / blk, blk, 0, stream>>>(h3, Wfc, bfc, outp, M);
    }
}

// Round 3
// 867.619 us; speedup vs baseline: 8.3599x; 1.1062x over previous
//
#include <hip/hip_runtime.h>
#include <cstddef>
#include <cstdint>

// GraphSAGE (3x SAGEConv mean-aggr + FC) on MI355X.
// Round 2: split-bf16 (hi+lo) MFMA GEMMs replace fp32 vector GEMMs.
//   C = Ah@Bh + Ah@Bl + Al@Bh  (~18-bit mantissa, approx fp32 quality)
//   128x128 tile, BK=32, 4 waves, global_load_lds width-16 staging,
//   both SAGE phases (mean@Wl + x@Wr) fused as K-extension.
// Activations exist only as bf16 hi/lo pairs; gathers read & write pairs.
// h3 pair aliases region0 (CSR + x pair + h1 pair, all dead before GEMM3).

typedef unsigned int uint_t;
typedef unsigned short ushort_t;
typedef __attribute__((ext_vector_type(8))) short short8;
typedef __attribute__((ext_vector_type(4))) float f32x4;

#define N_IN 64
#define N_HID 128
#define N_OUT 9

__device__ __forceinline__ ushort_t f2bf(float f) {   // fp32 -> bf16 RNE
    uint_t u = __float_as_uint(f);
    u += 0x7fffu + ((u >> 16) & 1u);
    return (ushort_t)(u >> 16);
}
__device__ __forceinline__ float bf2f(ushort_t h) {
    return __uint_as_float(((uint_t)h) << 16);
}
__device__ __forceinline__ void async_ld16(const void* g, void* l) {
    __builtin_amdgcn_global_load_lds((const __attribute__((address_space(1))) void*)g,
                                     (__attribute__((address_space(3))) void*)l, 16, 0, 0);
}

// ---------------- CSR build ----------------
__global__ void deg_int_kernel(const int* __restrict__ dst, int* __restrict__ degi, int E) {
    int t = blockIdx.x * 256 + threadIdx.x;
    if (t < E) atomicAdd(&degi[dst[t]], 1);
}

__global__ __launch_bounds__(256) void block_sum_kernel(const int* __restrict__ degi,
                                                        int* __restrict__ partial, int M) {
    __shared__ int sm[256];
    int i = blockIdx.x * 256 + threadIdx.x;
    sm[threadIdx.x] = (i < M) ? degi[i] : 0;
    __syncthreads();
    for (int s = 128; s > 0; s >>= 1) {
        if (threadIdx.x < s) sm[threadIdx.x] += sm[threadIdx.x + s];
        __syncthreads();
    }
    if (threadIdx.x == 0) partial[blockIdx.x] = sm[0];
}

__global__ void top_scan_kernel(int* __restrict__ partial, int nb) {
    if (blockIdx.x == 0 && threadIdx.x == 0) {
        int run = 0;
        for (int b = 0; b < nb; ++b) { int v = partial[b]; partial[b] = run; run += v; }
    }
}

__global__ __launch_bounds__(256) void apply_scan_kernel(
    const int* __restrict__ degi, const int* __restrict__ partial,
    int* __restrict__ row_start, int* __restrict__ cursor,
    float* __restrict__ invdeg, int M)
{
    __shared__ int sm[256];
    int i = blockIdx.x * 256 + threadIdx.x;
    int d = (i < M) ? degi[i] : 0;
    sm[threadIdx.x] = d;
    __syncthreads();
    for (int off = 1; off < 256; off <<= 1) {
        int v = (threadIdx.x >= off) ? sm[threadIdx.x - off] : 0;
        __syncthreads();
        sm[threadIdx.x] += v;
        __syncthreads();
    }
    if (i < M) {
        int rs = partial[blockIdx.x] + sm[threadIdx.x] - d;
        row_start[i] = rs;
        cursor[i] = rs;
        invdeg[i] = 1.0f / fmaxf((float)d, 1.0f);
    }
}

__global__ void fill_kernel(const int* __restrict__ src, const int* __restrict__ dst,
                            int* __restrict__ cursor, int* __restrict__ colA, int E) {
    int e = blockIdx.x * 256 + threadIdx.x;
    if (e < E) {
        int p = atomicAdd(&cursor[dst[e]], 1);
        colA[p] = src[e];
    }
}

// ---------------- splits ----------------
__global__ void split_kernel(const float* __restrict__ X, ushort_t* __restrict__ xh,
                             ushort_t* __restrict__ xl, int n) {
    int idx = blockIdx.x * 256 + threadIdx.x;
    if (idx < n) {
        float v = X[idx];
        ushort_t hb = f2bf(v);
        xh[idx] = hb;
        xl[idx] = f2bf(v - bf2f(hb));
    }
}

// W [K][N] fp32 -> transposed split Wt_hi/Wt_lo [N][K] bf16
__global__ void wsplit_kernel(const float* __restrict__ W, ushort_t* __restrict__ th,
                              ushort_t* __restrict__ tl, int K, int N) {
    int idx = blockIdx.x * 256 + threadIdx.x;
    if (idx >= K * N) return;
    int k = idx / N, n = idx - k * N;
    float v = W[idx];
    ushort_t hb = f2bf(v);
    th[(size_t)n * K + k] = hb;
    tl[(size_t)n * K + k] = f2bf(v - bf2f(hb));
}

// ---------------- gather-mean: fp32 source (layer 1), DIM=64 ----------------
__global__ __launch_bounds__(256) void gather_mean_f32(
    const float* __restrict__ feat, const int* __restrict__ colA,
    const int* __restrict__ row_start, const int* __restrict__ degi,
    const float* __restrict__ invdeg,
    ushort_t* __restrict__ oh, ushort_t* __restrict__ ol, int M)
{
    const int tid = threadIdx.x;
    const int slot = tid >> 4;
    const int ch = tid & 15;
    const int node = blockIdx.x * 16 + slot;
    if (node >= M) return;
    const int beg = row_start[node];
    const int cnt = degi[node];
    float4 acc = make_float4(0.f, 0.f, 0.f, 0.f);
    int j = 0;
    for (; j + 1 < cnt; j += 2) {
        const int s0 = colA[beg + j];
        const int s1 = colA[beg + j + 1];
        const float4 v0 = *(const float4*)(feat + (size_t)s0 * 64 + ch * 4);
        const float4 v1 = *(const float4*)(feat + (size_t)s1 * 64 + ch * 4);
        acc.x += v0.x + v1.x; acc.y += v0.y + v1.y;
        acc.z += v0.z + v1.z; acc.w += v0.w + v1.w;
    }
    if (j < cnt) {
        const int s0 = colA[beg + j];
        const float4 v0 = *(const float4*)(feat + (size_t)s0 * 64 + ch * 4);
        acc.x += v0.x; acc.y += v0.y; acc.z += v0.z; acc.w += v0.w;
    }
    const float sc = invdeg[node];
    float m0 = acc.x * sc, m1 = acc.y * sc, m2 = acc.z * sc, m3 = acc.w * sc;
    ushort_t h0 = f2bf(m0), h1 = f2bf(m1), h2 = f2bf(m2), h3 = f2bf(m3);
    ushort_t l0 = f2bf(m0 - bf2f(h0)), l1 = f2bf(m1 - bf2f(h1));
    ushort_t l2 = f2bf(m2 - bf2f(h2)), l3 = f2bf(m3 - bf2f(h3));
    uint2 hv = make_uint2((uint_t)h0 | ((uint_t)h1 << 16), (uint_t)h2 | ((uint_t)h3 << 16));
    uint2 lv = make_uint2((uint_t)l0 | ((uint_t)l1 << 16), (uint_t)l2 | ((uint_t)l3 << 16));
    *(uint2*)(oh + (size_t)node * 64 + ch * 4) = hv;
    *(uint2*)(ol + (size_t)node * 64 + ch * 4) = lv;
}

// ---------------- gather-mean: bf16-pair source (layers 2/3), DIM=128 ----------------
__device__ __forceinline__ void acc_pair(float* a, uint4 h, uint4 l) {
    a[0] += __uint_as_float(h.x << 16) + __uint_as_float(l.x << 16);
    a[1] += __uint_as_float(h.x & 0xffff0000u) + __uint_as_float(l.x & 0xffff0000u);
    a[2] += __uint_as_float(h.y << 16) + __uint_as_float(l.y << 16);
    a[3] += __uint_as_float(h.y & 0xffff0000u) + __uint_as_float(l.y & 0xffff0000u);
    a[4] += __uint_as_float(h.z << 16) + __uint_as_float(l.z << 16);
    a[5] += __uint_as_float(h.z & 0xffff0000u) + __uint_as_float(l.z & 0xffff0000u);
    a[6] += __uint_as_float(h.w << 16) + __uint_as_float(l.w << 16);
    a[7] += __uint_as_float(h.w & 0xffff0000u) + __uint_as_float(l.w & 0xffff0000u);
}

__global__ __launch_bounds__(256) void gather_mean_pair(
    const ushort_t* __restrict__ fh, const ushort_t* __restrict__ fl,
    const int* __restrict__ colA, const int* __restrict__ row_start,
    const int* __restrict__ degi, const float* __restrict__ invdeg,
    ushort_t* __restrict__ oh, ushort_t* __restrict__ ol, int M)
{
    const int tid = threadIdx.x;
    const int slot = tid >> 4;
    const int ch = tid & 15;
    const int node = blockIdx.x * 16 + slot;
    if (node >= M) return;
    const int beg = row_start[node];
    const int cnt = degi[node];
    float a[8];
#pragma unroll
    for (int t = 0; t < 8; ++t) a[t] = 0.f;
    int j = 0;
    for (; j + 1 < cnt; j += 2) {
        const int s0 = colA[beg + j];
        const int s1 = colA[beg + j + 1];
        const uint4 h0 = *(const uint4*)(fh + (size_t)s0 * 128 + ch * 8);
        const uint4 l0 = *(const uint4*)(fl + (size_t)s0 * 128 + ch * 8);
        const uint4 h1 = *(const uint4*)(fh + (size_t)s1 * 128 + ch * 8);
        const uint4 l1 = *(const uint4*)(fl + (size_t)s1 * 128 + ch * 8);
        acc_pair(a, h0, l0);
        acc_pair(a, h1, l1);
    }
    if (j < cnt) {
        const int s0 = colA[beg + j];
        const uint4 h0 = *(const uint4*)(fh + (size_t)s0 * 128 + ch * 8);
        const uint4 l0 = *(const uint4*)(fl + (size_t)s0 * 128 + ch * 8);
        acc_pair(a, h0, l0);
    }
    const float sc = invdeg[node];
    uint_t hv[4], lv[4];
#pragma unroll
    for (int t = 0; t < 4; ++t) {
        float m0 = a[2 * t] * sc, m1 = a[2 * t + 1] * sc;
        ushort_t hb0 = f2bf(m0), hb1 = f2bf(m1);
        ushort_t lb0 = f2bf(m0 - bf2f(hb0)), lb1 = f2bf(m1 - bf2f(hb1));
        hv[t] = (uint_t)hb0 | ((uint_t)hb1 << 16);
        lv[t] = (uint_t)lb0 | ((uint_t)lb1 << 16);
    }
    *(uint4*)(oh + (size_t)node * 128 + ch * 8) = make_uint4(hv[0], hv[1], hv[2], hv[3]);
    *(uint4*)(ol + (size_t)node * 128 + ch * 8) = make_uint4(lv[0], lv[1], lv[2], lv[3]);
}

// ---------------- split-bf16 MFMA GEMM ----------------
// out = relu( mean @ Wl + x @ Wr + bias ), all operands bf16 hi/lo pairs.
// A: [M][K] row-major pairs. B: Wt [N][K] row-major pairs (pre-transposed).
// 128x128 tile, BK=32, 4 waves (2x2), each wave 64x64 via 4x4 16x16x32 MFMAs,
// 3 split terms: hh + hl + lh.
__global__ __launch_bounds__(256) void mfma_sage_gemm(
    const ushort_t* __restrict__ Amh, const ushort_t* __restrict__ Aml,
    const ushort_t* __restrict__ Axh, const ushort_t* __restrict__ Axl,
    const ushort_t* __restrict__ Blh, const ushort_t* __restrict__ Bll,
    const ushort_t* __restrict__ Brh, const ushort_t* __restrict__ Brl,
    const float* __restrict__ bias,
    ushort_t* __restrict__ Oh, ushort_t* __restrict__ Ol,
    int M, int K, int N)
{
    __shared__ ushort_t As_h[128 * 32];
    __shared__ ushort_t As_l[128 * 32];
    __shared__ ushort_t Bs_h[128 * 32];
    __shared__ ushort_t Bs_l[128 * 32];

    const int tid  = threadIdx.x;
    const int lane = tid & 63;
    const int wave = tid >> 6;
    const int wm = (wave & 1) * 64;
    const int wn = (wave >> 1) * 64;
    const int l15 = lane & 15;
    const int quad = lane >> 4;
    const int bm = blockIdx.x * 128;
    const int bn = blockIdx.y * 128;

    const int ar = tid >> 2;          // staging row chunk 0..63
    const int ac = (tid & 3) * 8;     // staging elem offset (16B)
    const int ldst = tid * 8;         // LDS ushort offset (= tid*16 bytes)

    f32x4 acc[4][4];
#pragma unroll
    for (int i = 0; i < 4; ++i)
#pragma unroll
        for (int j = 0; j < 4; ++j) acc[i][j] = (f32x4){0.f, 0.f, 0.f, 0.f};

    for (int phase = 0; phase < 2; ++phase) {
        const ushort_t* __restrict__ Ah = phase ? Axh : Amh;
        const ushort_t* __restrict__ Al = phase ? Axl : Aml;
        const ushort_t* __restrict__ Bh = phase ? Brh : Blh;
        const ushort_t* __restrict__ Bl = phase ? Brl : Bll;
        for (int k0 = 0; k0 < K; k0 += 32) {
            __syncthreads();   // protect LDS reuse
            const size_t a0 = (size_t)(bm + ar) * K + k0 + ac;
            const size_t a1 = a0 + (size_t)64 * K;
            const size_t b0 = (size_t)(bn + ar) * K + k0 + ac;
            const size_t b1 = b0 + (size_t)64 * K;
            async_ld16(Ah + a0, &As_h[ldst]);
            async_ld16(Ah + a1, &As_h[2048 + ldst]);
            async_ld16(Al + a0, &As_l[ldst]);
            async_ld16(Al + a1, &As_l[2048 + ldst]);
            async_ld16(Bh + b0, &Bs_h[ldst]);
            async_ld16(Bh + b1, &Bs_h[2048 + ldst]);
            async_ld16(Bl + b0, &Bs_l[ldst]);
            async_ld16(Bl + b1, &Bs_l[2048 + ldst]);
            __syncthreads();   // drains vmcnt (global_load_lds) per guide

            short8 fah[4], fal[4], fbh[4], fbl[4];
#pragma unroll
            for (int i = 0; i < 4; ++i) {
                const int aoff = (wm + i * 16 + l15) * 32 + quad * 8;
                const int boff = (wn + i * 16 + l15) * 32 + quad * 8;
                fah[i] = *(const short8*)&As_h[aoff];
                fal[i] = *(const short8*)&As_l[aoff];
                fbh[i] = *(const short8*)&Bs_h[boff];
                fbl[i] = *(const short8*)&Bs_l[boff];
            }
#pragma unroll
            for (int i = 0; i < 4; ++i)
#pragma unroll
                for (int j = 0; j < 4; ++j) {
                    acc[i][j] = __builtin_amdgcn_mfma_f32_16x16x32_bf16(fah[i], fbh[j], acc[i][j], 0, 0, 0);
                    acc[i][j] = __builtin_amdgcn_mfma_f32_16x16x32_bf16(fah[i], fbl[j], acc[i][j], 0, 0, 0);
                    acc[i][j] = __builtin_amdgcn_mfma_f32_16x16x32_bf16(fal[i], fbh[j], acc[i][j], 0, 0, 0);
                }
        }
    }

    // epilogue: bias + relu + hi/lo split store
#pragma unroll
    for (int i = 0; i < 4; ++i) {
        const int row0 = bm + wm + i * 16 + quad * 4;
#pragma unroll
        for (int j = 0; j < 4; ++j) {
            const int col = bn + wn + j * 16 + l15;
            const float bv = bias[col];
#pragma unroll
            for (int r = 0; r < 4; ++r) {
                const int row = row0 + r;
                if (row < M) {
                    float y = acc[i][j][r] + bv;
                    y = fmaxf(y, 0.f);
                    const ushort_t hb = f2bf(y);
                    const ushort_t lb = f2bf(y - bf2f(hb));
                    Oh[(size_t)row * N + col] = hb;
                    Ol[(size_t)row * N + col] = lb;
                }
            }
        }
    }
}

// ---------------- final FC: reads h3 pair, K=256, N=9 ----------------
__global__ __launch_bounds__(256) void fc_pair_kernel(
    const ushort_t* __restrict__ hh, const ushort_t* __restrict__ hl,
    const float* __restrict__ W, const float* __restrict__ b,
    float* __restrict__ outp, int M)
{
    __shared__ float Ws[256 * N_OUT];
    __shared__ float bs[N_OUT];
    for (int i = threadIdx.x; i < 256 * N_OUT; i += 256) Ws[i] = W[i];
    if (threadIdx.x < N_OUT) bs[threadIdx.x] = b[threadIdx.x];
    __syncthreads();
    const int t = blockIdx.x * 256 + threadIdx.x;
    if (t >= M * N_OUT) return;
    const int i = t / N_OUT;
    const int j = t - i * N_OUT;
    const ushort_t* __restrict__ rh = hh + (size_t)i * 256;
    const ushort_t* __restrict__ rl = hl + (size_t)i * 256;
    float s = bs[j];
#pragma unroll 8
    for (int k = 0; k < 256; k += 2) {
        uint_t uh = *(const uint_t*)(rh + k);
        uint_t ul = *(const uint_t*)(rl + k);
        float a0 = __uint_as_float(uh << 16) + __uint_as_float(ul << 16);
        float a1 = __uint_as_float(uh & 0xffff0000u) + __uint_as_float(ul & 0xffff0000u);
        s += a0 * Ws[k * N_OUT + j] + a1 * Ws[(k + 1) * N_OUT + j];
    }
    outp[t] = s;
}

extern "C" void kernel_launch(void* const* d_in, const int* in_sizes, int n_in,
                              void* d_out, int out_size, void* d_ws, size_t ws_size,
                              hipStream_t stream) {
    const float* x   = (const float*)d_in[0];
    const int*   ei  = (const int*)d_in[1];
    const float* Wl1 = (const float*)d_in[2];
    const float* bl1 = (const float*)d_in[3];
    const float* Wr1 = (const float*)d_in[4];
    const float* Wl2 = (const float*)d_in[5];
    const float* bl2 = (const float*)d_in[6];
    const float* Wr2 = (const float*)d_in[7];
    const float* Wl3 = (const float*)d_in[8];
    const float* bl3 = (const float*)d_in[9];
    const float* Wr3 = (const float*)d_in[10];
    const float* Wfc = (const float*)d_in[11];
    const float* bfc = (const float*)d_in[12];
    float* outp = (float*)d_out;

    const int M = in_sizes[0] / N_IN;        // 100000
    const int E = in_sizes[1] / 2;           // 1600000
    const int* src = ei;
    const int* dst = ei + E;
    const int NB = (M + 255) / 256;
    const size_t Mrow = (size_t)NB * 256;    // 100352, covers gemm OOB rows

    // -------- workspace carve --------
    char* base = (char*)d_ws;
    char* p = base;
    // region0: dead before GEMM3; aliased by h3 pair
    int*   degi      = (int*)p;   p += Mrow * 4;
    int*   row_start = (int*)p;   p += Mrow * 4;
    int*   cursor    = (int*)p;   p += Mrow * 4;
    int*   partial   = (int*)p;   p += 4096;
    float* invdeg    = (float*)p; p += Mrow * 4;
    int*   colA      = (int*)p;   p += ((size_t)E + 3) / 4 * 16;
    ushort_t* xh     = (ushort_t*)p; p += Mrow * 64 * 2;
    ushort_t* xl     = (ushort_t*)p; p += Mrow * 64 * 2;
    ushort_t* h1h    = (ushort_t*)p; p += Mrow * 128 * 2;
    ushort_t* h1l    = (ushort_t*)p; p += Mrow * 128 * 2;
    size_t r0_used = (size_t)(p - base);
    size_t h3_need = 2 * Mrow * 256 * 2;     // ~102.5 MB
    ushort_t* h3h = (ushort_t*)base;
    ushort_t* h3l = (ushort_t*)(base + Mrow * 256 * 2);
    p = base + (r0_used > h3_need ? r0_used : h3_need);
    // persistent-through-GEMM3 buffers
    ushort_t* aggh = (ushort_t*)p; p += Mrow * 128 * 2;
    ushort_t* aggl = (ushort_t*)p; p += Mrow * 128 * 2;
    ushort_t* h2h  = (ushort_t*)p; p += Mrow * 128 * 2;
    ushort_t* h2l  = (ushort_t*)p; p += Mrow * 128 * 2;
    ushort_t* w1lh = (ushort_t*)p; p += 64 * 128 * 2;
    ushort_t* w1ll = (ushort_t*)p; p += 64 * 128 * 2;
    ushort_t* w1rh = (ushort_t*)p; p += 64 * 128 * 2;
    ushort_t* w1rl = (ushort_t*)p; p += 64 * 128 * 2;
    ushort_t* w2lh = (ushort_t*)p; p += 128 * 128 * 2;
    ushort_t* w2ll = (ushort_t*)p; p += 128 * 128 * 2;
    ushort_t* w2rh = (ushort_t*)p; p += 128 * 128 * 2;
    ushort_t* w2rl = (ushort_t*)p; p += 128 * 128 * 2;
    ushort_t* w3lh = (ushort_t*)p; p += 128 * 256 * 2;
    ushort_t* w3ll = (ushort_t*)p; p += 128 * 256 * 2;
    ushort_t* w3rh = (ushort_t*)p; p += 128 * 256 * 2;
    ushort_t* w3rl = (ushort_t*)p; p += 128 * 256 * 2;
    (void)ws_size; (void)n_in; (void)out_size;

    const int blk = 256;
    const int grid_m = (M + 127) / 128;      // 782

    // -------- CSR build --------
    hipMemsetAsync(degi, 0, Mrow * 4, stream);
    deg_int_kernel<<<(E + blk - 1) / blk, blk, 0, stream>>>(dst, degi, E);
    block_sum_kernel<<<NB, blk, 0, stream>>>(degi, partial, M);
    top_scan_kernel<<<1, 64, 0, stream>>>(partial, NB);
    apply_scan_kernel<<<NB, blk, 0, stream>>>(degi, partial, row_start, cursor, invdeg, M);
    fill_kernel<<<(E + blk - 1) / blk, blk, 0, stream>>>(src, dst, cursor, colA, E);

    // -------- splits --------
    split_kernel<<<((M * 64) + blk - 1) / blk, blk, 0, stream>>>(x, xh, xl, M * 64);
    wsplit_kernel<<<(64 * 128 + blk - 1) / blk, blk, 0, stream>>>(Wl1, w1lh, w1ll, 64, 128);
    wsplit_kernel<<<(64 * 128 + blk - 1) / blk, blk, 0, stream>>>(Wr1, w1rh, w1rl, 64, 128);
    wsplit_kernel<<<(128 * 128 + blk - 1) / blk, blk, 0, stream>>>(Wl2, w2lh, w2ll, 128, 128);
    wsplit_kernel<<<(128 * 128 + blk - 1) / blk, blk, 0, stream>>>(Wr2, w2rh, w2rl, 128, 128);
    wsplit_kernel<<<(128 * 256 + blk - 1) / blk, blk, 0, stream>>>(Wl3, w3lh, w3ll, 128, 256);
    wsplit_kernel<<<(128 * 256 + blk - 1) / blk, blk, 0, stream>>>(Wr3, w3rh, w3rl, 128, 256);

    // -------- layer 1: 64 -> 128 --------
    gather_mean_f32<<<(M + 15) / 16, blk, 0, stream>>>(
        x, colA, row_start, degi, invdeg, aggh, aggl, M);
    mfma_sage_gemm<<<dim3(grid_m, 1), blk, 0, stream>>>(
        aggh, aggl, xh, xl, w1lh, w1ll, w1rh, w1rl, bl1, h1h, h1l, M, 64, 128);

    // -------- layer 2: 128 -> 128 --------
    gather_mean_pair<<<(M + 15) / 16, blk, 0, stream>>>(
        h1h, h1l, colA, row_start, degi, invdeg, aggh, aggl, M);
    mfma_sage_gemm<<<dim3(grid_m, 1), blk, 0, stream>>>(
        aggh, aggl, h1h, h1l, w2lh, w2ll, w2rh, w2rl, bl2, h2h, h2l, M, 128, 128);

    // -------- layer 3: 128 -> 256 (h3 pair overwrites region0) --------
    gather_mean_pair<<<(M + 15) / 16, blk, 0, stream>>>(
        h2h, h2l, colA, row_start, degi, invdeg, aggh, aggl, M);
    mfma_sage_gemm<<<dim3(grid_m, 2), blk, 0, stream>>>(
        aggh, aggl, h2h, h2l, w3lh, w3ll, w3rh, w3rl, bl3, h3h, h3l, M, 128, 256);

    // -------- final FC --------
    fc_pair_kernel<<<(M * N_OUT + blk - 1) / blk, blk, 0, stream>>>(
        h3h, h3l, Wfc, bfc, outp, M);
}

// Round 4
// 608.574 us; speedup vs baseline: 11.9184x; 1.4257x over previous
//
#include <hip/hip_runtime.h>
#include <cstddef>
#include <cstdint>

// GraphSAGE (3x SAGEConv mean-aggr + FC) on MI355X.
// Round 3:
//  - gathers read ONLY the hi (bf16) feature table: halves gather traffic;
//    mean still computed fp32, re-split to hi/lo pair for the MFMA GEMM.
//  - CSR build: fused degree+rank atomic pass -> atomic-free fill;
//    parallel single-block top-level scan (was 1-thread latency chain).
//  - split-bf16 MFMA GEMMs unchanged (C = Ah@Bh + Ah@Bl + Al@Bh).

typedef unsigned int uint_t;
typedef unsigned short ushort_t;
typedef __attribute__((ext_vector_type(8))) short short8;
typedef __attribute__((ext_vector_type(4))) float f32x4;

#define N_IN 64
#define N_HID 128
#define N_OUT 9

__device__ __forceinline__ ushort_t f2bf(float f) {   // fp32 -> bf16 RNE
    uint_t u = __float_as_uint(f);
    u += 0x7fffu + ((u >> 16) & 1u);
    return (ushort_t)(u >> 16);
}
__device__ __forceinline__ float bf2f(ushort_t h) {
    return __uint_as_float(((uint_t)h) << 16);
}
__device__ __forceinline__ void async_ld16(const void* g, void* l) {
    __builtin_amdgcn_global_load_lds((const __attribute__((address_space(1))) void*)g,
                                     (__attribute__((address_space(3))) void*)l, 16, 0, 0);
}

// ---------------- CSR build ----------------
// fused degree histogram + per-edge rank (position within dst bucket)
__global__ void rank_kernel(const int* __restrict__ dst, int* __restrict__ degi,
                            int* __restrict__ rank, int E) {
    int e = blockIdx.x * 256 + threadIdx.x;
    if (e < E) rank[e] = atomicAdd(&degi[dst[e]], 1);
}

__global__ __launch_bounds__(256) void block_sum_kernel(const int* __restrict__ degi,
                                                        int* __restrict__ partial, int M) {
    __shared__ int sm[256];
    int i = blockIdx.x * 256 + threadIdx.x;
    sm[threadIdx.x] = (i < M) ? degi[i] : 0;
    __syncthreads();
    for (int s = 128; s > 0; s >>= 1) {
        if (threadIdx.x < s) sm[threadIdx.x] += sm[threadIdx.x + s];
        __syncthreads();
    }
    if (threadIdx.x == 0) partial[blockIdx.x] = sm[0];
}

// single-block parallel exclusive scan over nb (<512) partials
__global__ __launch_bounds__(512) void top_scan_par(int* __restrict__ partial, int nb) {
    __shared__ int sm[512];
    const int i = threadIdx.x;
    const int v = (i < nb) ? partial[i] : 0;
    sm[i] = v;
    __syncthreads();
    for (int off = 1; off < 512; off <<= 1) {
        int t = (i >= off) ? sm[i - off] : 0;
        __syncthreads();
        sm[i] += t;
        __syncthreads();
    }
    if (i < nb) partial[i] = sm[i] - v;   // exclusive
}

__global__ __launch_bounds__(256) void apply_scan_kernel(
    const int* __restrict__ degi, const int* __restrict__ partial,
    int* __restrict__ row_start, float* __restrict__ invdeg, int M)
{
    __shared__ int sm[256];
    int i = blockIdx.x * 256 + threadIdx.x;
    int d = (i < M) ? degi[i] : 0;
    sm[threadIdx.x] = d;
    __syncthreads();
    for (int off = 1; off < 256; off <<= 1) {
        int v = (threadIdx.x >= off) ? sm[threadIdx.x - off] : 0;
        __syncthreads();
        sm[threadIdx.x] += v;
        __syncthreads();
    }
    if (i < M) {
        row_start[i] = partial[blockIdx.x] + sm[threadIdx.x] - d;  // exclusive prefix
        invdeg[i] = 1.0f / fmaxf((float)d, 1.0f);
    }
}

// atomic-free fill: p = row_start[dst[e]] + rank[e]
__global__ void fill_kernel(const int* __restrict__ src, const int* __restrict__ dst,
                            const int* __restrict__ row_start, const int* __restrict__ rank,
                            int* __restrict__ colA, int E) {
    int e = blockIdx.x * 256 + threadIdx.x;
    if (e < E) colA[row_start[dst[e]] + rank[e]] = src[e];
}

// ---------------- splits ----------------
__global__ void split_kernel(const float* __restrict__ X, ushort_t* __restrict__ xh,
                             ushort_t* __restrict__ xl, int n) {
    int idx = blockIdx.x * 256 + threadIdx.x;
    if (idx < n) {
        float v = X[idx];
        ushort_t hb = f2bf(v);
        xh[idx] = hb;
        xl[idx] = f2bf(v - bf2f(hb));
    }
}

// W [K][N] fp32 -> transposed split Wt_hi/Wt_lo [N][K] bf16
__global__ void wsplit_kernel(const float* __restrict__ W, ushort_t* __restrict__ th,
                              ushort_t* __restrict__ tl, int K, int N) {
    int idx = blockIdx.x * 256 + threadIdx.x;
    if (idx >= K * N) return;
    int k = idx / N, n = idx - k * N;
    float v = W[idx];
    ushort_t hb = f2bf(v);
    th[(size_t)n * K + k] = hb;
    tl[(size_t)n * K + k] = f2bf(v - bf2f(hb));
}

// ---------------- gather-mean (hi-only input, pair output) ----------------
__device__ __forceinline__ void acc8_hi(float* a, uint4 h) {
    a[0] += __uint_as_float(h.x << 16);
    a[1] += __uint_as_float(h.x & 0xffff0000u);
    a[2] += __uint_as_float(h.y << 16);
    a[3] += __uint_as_float(h.y & 0xffff0000u);
    a[4] += __uint_as_float(h.z << 16);
    a[5] += __uint_as_float(h.z & 0xffff0000u);
    a[6] += __uint_as_float(h.w << 16);
    a[7] += __uint_as_float(h.w & 0xffff0000u);
}

// CH threads per node, each owns 8 bf16 elems (16B uint4 loads); DIM = CH*8
template <int CH>
__global__ __launch_bounds__(256) void gather_mean_hi(
    const ushort_t* __restrict__ fh, const int* __restrict__ colA,
    const int* __restrict__ row_start, const int* __restrict__ degi,
    const float* __restrict__ invdeg,
    ushort_t* __restrict__ oh, ushort_t* __restrict__ ol, int M)
{
    constexpr int SLOTS = 256 / CH;
    constexpr int DIM = CH * 8;
    const int tid = threadIdx.x;
    const int slot = tid / CH;
    const int ch = tid % CH;
    const int node = blockIdx.x * SLOTS + slot;
    if (node >= M) return;
    const int beg = row_start[node];
    const int cnt = degi[node];
    float a[8];
#pragma unroll
    for (int t = 0; t < 8; ++t) a[t] = 0.f;
    int j = 0;
    for (; j + 1 < cnt; j += 2) {
        const int s0 = colA[beg + j];
        const int s1 = colA[beg + j + 1];
        const uint4 h0 = *(const uint4*)(fh + (size_t)s0 * DIM + ch * 8);
        const uint4 h1 = *(const uint4*)(fh + (size_t)s1 * DIM + ch * 8);
        acc8_hi(a, h0);
        acc8_hi(a, h1);
    }
    if (j < cnt) {
        const int s0 = colA[beg + j];
        const uint4 h0 = *(const uint4*)(fh + (size_t)s0 * DIM + ch * 8);
        acc8_hi(a, h0);
    }
    const float sc = invdeg[node];
    uint_t hv[4], lv[4];
#pragma unroll
    for (int t = 0; t < 4; ++t) {
        float m0 = a[2 * t] * sc, m1 = a[2 * t + 1] * sc;
        ushort_t hb0 = f2bf(m0), hb1 = f2bf(m1);
        ushort_t lb0 = f2bf(m0 - bf2f(hb0)), lb1 = f2bf(m1 - bf2f(hb1));
        hv[t] = (uint_t)hb0 | ((uint_t)hb1 << 16);
        lv[t] = (uint_t)lb0 | ((uint_t)lb1 << 16);
    }
    *(uint4*)(oh + (size_t)node * DIM + ch * 8) = make_uint4(hv[0], hv[1], hv[2], hv[3]);
    *(uint4*)(ol + (size_t)node * DIM + ch * 8) = make_uint4(lv[0], lv[1], lv[2], lv[3]);
}

// ---------------- split-bf16 MFMA GEMM ----------------
// out = relu( mean @ Wl + x @ Wr + bias ), all operands bf16 hi/lo pairs.
// A: [M][K] row-major pairs. B: Wt [N][K] row-major pairs (pre-transposed).
// 128x128 tile, BK=32, 4 waves (2x2), each wave 64x64 via 4x4 16x16x32 MFMAs,
// 3 split terms: hh + hl + lh.
__global__ __launch_bounds__(256) void mfma_sage_gemm(
    const ushort_t* __restrict__ Amh, const ushort_t* __restrict__ Aml,
    const ushort_t* __restrict__ Axh, const ushort_t* __restrict__ Axl,
    const ushort_t* __restrict__ Blh, const ushort_t* __restrict__ Bll,
    const ushort_t* __restrict__ Brh, const ushort_t* __restrict__ Brl,
    const float* __restrict__ bias,
    ushort_t* __restrict__ Oh, ushort_t* __restrict__ Ol,
    int M, int K, int N)
{
    __shared__ ushort_t As_h[128 * 32];
    __shared__ ushort_t As_l[128 * 32];
    __shared__ ushort_t Bs_h[128 * 32];
    __shared__ ushort_t Bs_l[128 * 32];

    const int tid  = threadIdx.x;
    const int lane = tid & 63;
    const int wave = tid >> 6;
    const int wm = (wave & 1) * 64;
    const int wn = (wave >> 1) * 64;
    const int l15 = lane & 15;
    const int quad = lane >> 4;
    const int bm = blockIdx.x * 128;
    const int bn = blockIdx.y * 128;

    const int ar = tid >> 2;          // staging row chunk 0..63
    const int ac = (tid & 3) * 8;     // staging elem offset (16B)
    const int ldst = tid * 8;         // LDS ushort offset (= tid*16 bytes)

    f32x4 acc[4][4];
#pragma unroll
    for (int i = 0; i < 4; ++i)
#pragma unroll
        for (int j = 0; j < 4; ++j) acc[i][j] = (f32x4){0.f, 0.f, 0.f, 0.f};

    for (int phase = 0; phase < 2; ++phase) {
        const ushort_t* __restrict__ Ah = phase ? Axh : Amh;
        const ushort_t* __restrict__ Al = phase ? Axl : Aml;
        const ushort_t* __restrict__ Bh = phase ? Brh : Blh;
        const ushort_t* __restrict__ Bl = phase ? Brl : Bll;
        for (int k0 = 0; k0 < K; k0 += 32) {
            __syncthreads();   // protect LDS reuse
            const size_t a0 = (size_t)(bm + ar) * K + k0 + ac;
            const size_t a1 = a0 + (size_t)64 * K;
            const size_t b0 = (size_t)(bn + ar) * K + k0 + ac;
            const size_t b1 = b0 + (size_t)64 * K;
            async_ld16(Ah + a0, &As_h[ldst]);
            async_ld16(Ah + a1, &As_h[2048 + ldst]);
            async_ld16(Al + a0, &As_l[ldst]);
            async_ld16(Al + a1, &As_l[2048 + ldst]);
            async_ld16(Bh + b0, &Bs_h[ldst]);
            async_ld16(Bh + b1, &Bs_h[2048 + ldst]);
            async_ld16(Bl + b0, &Bs_l[ldst]);
            async_ld16(Bl + b1, &Bs_l[2048 + ldst]);
            __syncthreads();   // drains vmcnt (global_load_lds) per guide

            short8 fah[4], fal[4], fbh[4], fbl[4];
#pragma unroll
            for (int i = 0; i < 4; ++i) {
                const int aoff = (wm + i * 16 + l15) * 32 + quad * 8;
                const int boff = (wn + i * 16 + l15) * 32 + quad * 8;
                fah[i] = *(const short8*)&As_h[aoff];
                fal[i] = *(const short8*)&As_l[aoff];
                fbh[i] = *(const short8*)&Bs_h[boff];
                fbl[i] = *(const short8*)&Bs_l[boff];
            }
#pragma unroll
            for (int i = 0; i < 4; ++i)
#pragma unroll
                for (int j = 0; j < 4; ++j) {
                    acc[i][j] = __builtin_amdgcn_mfma_f32_16x16x32_bf16(fah[i], fbh[j], acc[i][j], 0, 0, 0);
                    acc[i][j] = __builtin_amdgcn_mfma_f32_16x16x32_bf16(fah[i], fbl[j], acc[i][j], 0, 0, 0);
                    acc[i][j] = __builtin_amdgcn_mfma_f32_16x16x32_bf16(fal[i], fbh[j], acc[i][j], 0, 0, 0);
                }
        }
    }

    // epilogue: bias + relu + hi/lo split store
#pragma unroll
    for (int i = 0; i < 4; ++i) {
        const int row0 = bm + wm + i * 16 + quad * 4;
#pragma unroll
        for (int j = 0; j < 4; ++j) {
            const int col = bn + wn + j * 16 + l15;
            const float bv = bias[col];
#pragma unroll
            for (int r = 0; r < 4; ++r) {
                const int row = row0 + r;
                if (row < M) {
                    float y = acc[i][j][r] + bv;
                    y = fmaxf(y, 0.f);
                    const ushort_t hb = f2bf(y);
                    const ushort_t lb = f2bf(y - bf2f(hb));
                    Oh[(size_t)row * N + col] = hb;
                    Ol[(size_t)row * N + col] = lb;
                }
            }
        }
    }
}

// ---------------- final FC: reads h3 pair, K=256, N=9 ----------------
__global__ __launch_bounds__(256) void fc_pair_kernel(
    const ushort_t* __restrict__ hh, const ushort_t* __restrict__ hl,
    const float* __restrict__ W, const float* __restrict__ b,
    float* __restrict__ outp, int M)
{
    __shared__ float Ws[256 * N_OUT];
    __shared__ float bs[N_OUT];
    for (int i = threadIdx.x; i < 256 * N_OUT; i += 256) Ws[i] = W[i];
    if (threadIdx.x < N_OUT) bs[threadIdx.x] = b[threadIdx.x];
    __syncthreads();
    const int t = blockIdx.x * 256 + threadIdx.x;
    if (t >= M * N_OUT) return;
    const int i = t / N_OUT;
    const int j = t - i * N_OUT;
    const ushort_t* __restrict__ rh = hh + (size_t)i * 256;
    const ushort_t* __restrict__ rl = hl + (size_t)i * 256;
    float s = bs[j];
#pragma unroll 8
    for (int k = 0; k < 256; k += 2) {
        uint_t uh = *(const uint_t*)(rh + k);
        uint_t ul = *(const uint_t*)(rl + k);
        float a0 = __uint_as_float(uh << 16) + __uint_as_float(ul << 16);
        float a1 = __uint_as_float(uh & 0xffff0000u) + __uint_as_float(ul & 0xffff0000u);
        s += a0 * Ws[k * N_OUT + j] + a1 * Ws[(k + 1) * N_OUT + j];
    }
    outp[t] = s;
}

extern "C" void kernel_launch(void* const* d_in, const int* in_sizes, int n_in,
                              void* d_out, int out_size, void* d_ws, size_t ws_size,
                              hipStream_t stream) {
    const float* x   = (const float*)d_in[0];
    const int*   ei  = (const int*)d_in[1];
    const float* Wl1 = (const float*)d_in[2];
    const float* bl1 = (const float*)d_in[3];
    const float* Wr1 = (const float*)d_in[4];
    const float* Wl2 = (const float*)d_in[5];
    const float* bl2 = (const float*)d_in[6];
    const float* Wr2 = (const float*)d_in[7];
    const float* Wl3 = (const float*)d_in[8];
    const float* bl3 = (const float*)d_in[9];
    const float* Wr3 = (const float*)d_in[10];
    const float* Wfc = (const float*)d_in[11];
    const float* bfc = (const float*)d_in[12];
    float* outp = (float*)d_out;

    const int M = in_sizes[0] / N_IN;        // 100000
    const int E = in_sizes[1] / 2;           // 1600000
    const int* src = ei;
    const int* dst = ei + E;
    const int NB = (M + 255) / 256;          // 391 (<512)
    const size_t Mrow = (size_t)NB * 256;    // 100096-rounded, covers gemm OOB rows

    // -------- workspace carve --------
    char* base = (char*)d_ws;
    char* p = base;
    // region0: dead before GEMM3; aliased by h3 pair
    int*   degi      = (int*)p;   p += Mrow * 4;
    int*   row_start = (int*)p;   p += Mrow * 4;
    int*   partial   = (int*)p;   p += 4096;
    float* invdeg    = (float*)p; p += Mrow * 4;
    int*   colA      = (int*)p;   p += ((size_t)E + 3) / 4 * 16;
    int*   rankb     = (int*)p;   p += ((size_t)E + 3) / 4 * 16;
    ushort_t* xh     = (ushort_t*)p; p += Mrow * 64 * 2;
    ushort_t* xl     = (ushort_t*)p; p += Mrow * 64 * 2;
    ushort_t* h1h    = (ushort_t*)p; p += Mrow * 128 * 2;
    ushort_t* h1l    = (ushort_t*)p; p += Mrow * 128 * 2;
    size_t r0_used = (size_t)(p - base);
    size_t h3_need = 2 * Mrow * 256 * 2;     // ~102.5 MB
    ushort_t* h3h = (ushort_t*)base;
    ushort_t* h3l = (ushort_t*)(base + Mrow * 256 * 2);
    p = base + (r0_used > h3_need ? r0_used : h3_need);
    // persistent-through-GEMM3 buffers
    ushort_t* aggh = (ushort_t*)p; p += Mrow * 128 * 2;
    ushort_t* aggl = (ushort_t*)p; p += Mrow * 128 * 2;
    ushort_t* h2h  = (ushort_t*)p; p += Mrow * 128 * 2;
    ushort_t* h2l  = (ushort_t*)p; p += Mrow * 128 * 2;
    ushort_t* w1lh = (ushort_t*)p; p += 64 * 128 * 2;
    ushort_t* w1ll = (ushort_t*)p; p += 64 * 128 * 2;
    ushort_t* w1rh = (ushort_t*)p; p += 64 * 128 * 2;
    ushort_t* w1rl = (ushort_t*)p; p += 64 * 128 * 2;
    ushort_t* w2lh = (ushort_t*)p; p += 128 * 128 * 2;
    ushort_t* w2ll = (ushort_t*)p; p += 128 * 128 * 2;
    ushort_t* w2rh = (ushort_t*)p; p += 128 * 128 * 2;
    ushort_t* w2rl = (ushort_t*)p; p += 128 * 128 * 2;
    ushort_t* w3lh = (ushort_t*)p; p += 128 * 256 * 2;
    ushort_t* w3ll = (ushort_t*)p; p += 128 * 256 * 2;
    ushort_t* w3rh = (ushort_t*)p; p += 128 * 256 * 2;
    ushort_t* w3rl = (ushort_t*)p; p += 128 * 256 * 2;
    (void)ws_size; (void)n_in; (void)out_size;

    const int blk = 256;
    const int grid_m = (M + 127) / 128;      // 782

    // -------- CSR build --------
    hipMemsetAsync(degi, 0, Mrow * 4, stream);
    rank_kernel<<<(E + blk - 1) / blk, blk, 0, stream>>>(dst, degi, rankb, E);
    block_sum_kernel<<<NB, blk, 0, stream>>>(degi, partial, M);
    top_scan_par<<<1, 512, 0, stream>>>(partial, NB);
    apply_scan_kernel<<<NB, blk, 0, stream>>>(degi, partial, row_start, invdeg, M);
    fill_kernel<<<(E + blk - 1) / blk, blk, 0, stream>>>(src, dst, row_start, rankb, colA, E);

    // -------- splits --------
    split_kernel<<<((M * 64) + blk - 1) / blk, blk, 0, stream>>>(x, xh, xl, M * 64);
    wsplit_kernel<<<(64 * 128 + blk - 1) / blk, blk, 0, stream>>>(Wl1, w1lh, w1ll, 64, 128);
    wsplit_kernel<<<(64 * 128 + blk - 1) / blk, blk, 0, stream>>>(Wr1, w1rh, w1rl, 64, 128);
    wsplit_kernel<<<(128 * 128 + blk - 1) / blk, blk, 0, stream>>>(Wl2, w2lh, w2ll, 128, 128);
    wsplit_kernel<<<(128 * 128 + blk - 1) / blk, blk, 0, stream>>>(Wr2, w2rh, w2rl, 128, 128);
    wsplit_kernel<<<(128 * 256 + blk - 1) / blk, blk, 0, stream>>>(Wl3, w3lh, w3ll, 128, 256);
    wsplit_kernel<<<(128 * 256 + blk - 1) / blk, blk, 0, stream>>>(Wr3, w3rh, w3rl, 128, 256);

    // -------- layer 1: 64 -> 128 (gather reads xh hi-only) --------
    gather_mean_hi<8><<<(M + 31) / 32, blk, 0, stream>>>(
        xh, colA, row_start, degi, invdeg, aggh, aggl, M);
    mfma_sage_gemm<<<dim3(grid_m, 1), blk, 0, stream>>>(
        aggh, aggl, xh, xl, w1lh, w1ll, w1rh, w1rl, bl1, h1h, h1l, M, 64, 128);

    // -------- layer 2: 128 -> 128 --------
    gather_mean_hi<16><<<(M + 15) / 16, blk, 0, stream>>>(
        h1h, colA, row_start, degi, invdeg, aggh, aggl, M);
    mfma_sage_gemm<<<dim3(grid_m, 1), blk, 0, stream>>>(
        aggh, aggl, h1h, h1l, w2lh, w2ll, w2rh, w2rl, bl2, h2h, h2l, M, 128, 128);

    // -------- layer 3: 128 -> 256 (h3 pair overwrites region0) --------
    gather_mean_hi<16><<<(M + 15) / 16, blk, 0, stream>>>(
        h2h, colA, row_start, degi, invdeg, aggh, aggl, M);
    mfma_sage_gemm<<<dim3(grid_m, 2), blk, 0, stream>>>(
        aggh, aggl, h2h, h2l, w3lh, w3ll, w3rh, w3rl, bl3, h3h, h3l, M, 128, 256);

    // -------- final FC --------
    fc_pair_kernel<<<(M * N_OUT + blk - 1) / blk, blk, 0, stream>>>(
        h3h, h3l, Wfc, bfc, outp, M);
}

// Round 5
// 566.459 us; speedup vs baseline: 12.8045x; 1.0743x over previous
//
#include <hip/hip_runtime.h>
#include <cstddef>
#include <cstdint>

// GraphSAGE (3x SAGEConv mean-aggr + FC) on MI355X.
// Round 4:
//  - hidden activations (h1,h2,h3) stored HI-ONLY (plain bf16); agg mean and
//    raw x keep hi/lo pairs; weights keep pairs. Self-phase GEMM = 2 MFMA
//    terms (Ah@Bh + Ah@Bl), mean-phase = 3 terms.
//  - GEMM LDS staging flipped to k-chunk-major (wave w stages k-chunk w,
//    dest = w*2048 + lane*16 B): ds_read_b128 fragment reads now 2-way
//    bank-aliased (free) instead of 8-way.
//  - CSR build (rank+fill atomic-free), hi-only gathers unchanged.

typedef unsigned int uint_t;
typedef unsigned short ushort_t;
typedef __attribute__((ext_vector_type(8))) short short8;
typedef __attribute__((ext_vector_type(4))) float f32x4;

#define N_IN 64
#define N_HID 128
#define N_OUT 9

__device__ __forceinline__ ushort_t f2bf(float f) {   // fp32 -> bf16 RNE
    uint_t u = __float_as_uint(f);
    u += 0x7fffu + ((u >> 16) & 1u);
    return (ushort_t)(u >> 16);
}
__device__ __forceinline__ float bf2f(ushort_t h) {
    return __uint_as_float(((uint_t)h) << 16);
}
__device__ __forceinline__ void async_ld16(const void* g, void* l) {
    __builtin_amdgcn_global_load_lds((const __attribute__((address_space(1))) void*)g,
                                     (__attribute__((address_space(3))) void*)l, 16, 0, 0);
}

// ---------------- CSR build ----------------
__global__ void rank_kernel(const int* __restrict__ dst, int* __restrict__ degi,
                            int* __restrict__ rank, int E) {
    int e = blockIdx.x * 256 + threadIdx.x;
    if (e < E) rank[e] = atomicAdd(&degi[dst[e]], 1);
}

__global__ __launch_bounds__(256) void block_sum_kernel(const int* __restrict__ degi,
                                                        int* __restrict__ partial, int M) {
    __shared__ int sm[256];
    int i = blockIdx.x * 256 + threadIdx.x;
    sm[threadIdx.x] = (i < M) ? degi[i] : 0;
    __syncthreads();
    for (int s = 128; s > 0; s >>= 1) {
        if (threadIdx.x < s) sm[threadIdx.x] += sm[threadIdx.x + s];
        __syncthreads();
    }
    if (threadIdx.x == 0) partial[blockIdx.x] = sm[0];
}

__global__ __launch_bounds__(512) void top_scan_par(int* __restrict__ partial, int nb) {
    __shared__ int sm[512];
    const int i = threadIdx.x;
    const int v = (i < nb) ? partial[i] : 0;
    sm[i] = v;
    __syncthreads();
    for (int off = 1; off < 512; off <<= 1) {
        int t = (i >= off) ? sm[i - off] : 0;
        __syncthreads();
        sm[i] += t;
        __syncthreads();
    }
    if (i < nb) partial[i] = sm[i] - v;   // exclusive
}

__global__ __launch_bounds__(256) void apply_scan_kernel(
    const int* __restrict__ degi, const int* __restrict__ partial,
    int* __restrict__ row_start, float* __restrict__ invdeg, int M)
{
    __shared__ int sm[256];
    int i = blockIdx.x * 256 + threadIdx.x;
    int d = (i < M) ? degi[i] : 0;
    sm[threadIdx.x] = d;
    __syncthreads();
    for (int off = 1; off < 256; off <<= 1) {
        int v = (threadIdx.x >= off) ? sm[threadIdx.x - off] : 0;
        __syncthreads();
        sm[threadIdx.x] += v;
        __syncthreads();
    }
    if (i < M) {
        row_start[i] = partial[blockIdx.x] + sm[threadIdx.x] - d;
        invdeg[i] = 1.0f / fmaxf((float)d, 1.0f);
    }
}

__global__ void fill_kernel(const int* __restrict__ src, const int* __restrict__ dst,
                            const int* __restrict__ row_start, const int* __restrict__ rank,
                            int* __restrict__ colA, int E) {
    int e = blockIdx.x * 256 + threadIdx.x;
    if (e < E) colA[row_start[dst[e]] + rank[e]] = src[e];
}

// ---------------- splits ----------------
__global__ void split_kernel(const float* __restrict__ X, ushort_t* __restrict__ xh,
                             ushort_t* __restrict__ xl, int n) {
    int idx = blockIdx.x * 256 + threadIdx.x;
    if (idx < n) {
        float v = X[idx];
        ushort_t hb = f2bf(v);
        xh[idx] = hb;
        xl[idx] = f2bf(v - bf2f(hb));
    }
}

__global__ void wsplit_kernel(const float* __restrict__ W, ushort_t* __restrict__ th,
                              ushort_t* __restrict__ tl, int K, int N) {
    int idx = blockIdx.x * 256 + threadIdx.x;
    if (idx >= K * N) return;
    int k = idx / N, n = idx - k * N;
    float v = W[idx];
    ushort_t hb = f2bf(v);
    th[(size_t)n * K + k] = hb;
    tl[(size_t)n * K + k] = f2bf(v - bf2f(hb));
}

// ---------------- gather-mean (hi-only input, pair output) ----------------
__device__ __forceinline__ void acc8_hi(float* a, uint4 h) {
    a[0] += __uint_as_float(h.x << 16);
    a[1] += __uint_as_float(h.x & 0xffff0000u);
    a[2] += __uint_as_float(h.y << 16);
    a[3] += __uint_as_float(h.y & 0xffff0000u);
    a[4] += __uint_as_float(h.z << 16);
    a[5] += __uint_as_float(h.z & 0xffff0000u);
    a[6] += __uint_as_float(h.w << 16);
    a[7] += __uint_as_float(h.w & 0xffff0000u);
}

template <int CH>
__global__ __launch_bounds__(256) void gather_mean_hi(
    const ushort_t* __restrict__ fh, const int* __restrict__ colA,
    const int* __restrict__ row_start, const int* __restrict__ degi,
    const float* __restrict__ invdeg,
    ushort_t* __restrict__ oh, ushort_t* __restrict__ ol, int M)
{
    constexpr int SLOTS = 256 / CH;
    constexpr int DIM = CH * 8;
    const int tid = threadIdx.x;
    const int slot = tid / CH;
    const int ch = tid % CH;
    const int node = blockIdx.x * SLOTS + slot;
    if (node >= M) return;
    const int beg = row_start[node];
    const int cnt = degi[node];
    float a[8];
#pragma unroll
    for (int t = 0; t < 8; ++t) a[t] = 0.f;
    int j = 0;
    for (; j + 1 < cnt; j += 2) {
        const int s0 = colA[beg + j];
        const int s1 = colA[beg + j + 1];
        const uint4 h0 = *(const uint4*)(fh + (size_t)s0 * DIM + ch * 8);
        const uint4 h1 = *(const uint4*)(fh + (size_t)s1 * DIM + ch * 8);
        acc8_hi(a, h0);
        acc8_hi(a, h1);
    }
    if (j < cnt) {
        const int s0 = colA[beg + j];
        const uint4 h0 = *(const uint4*)(fh + (size_t)s0 * DIM + ch * 8);
        acc8_hi(a, h0);
    }
    const float sc = invdeg[node];
    uint_t hv[4], lv[4];
#pragma unroll
    for (int t = 0; t < 4; ++t) {
        float m0 = a[2 * t] * sc, m1 = a[2 * t + 1] * sc;
        ushort_t hb0 = f2bf(m0), hb1 = f2bf(m1);
        ushort_t lb0 = f2bf(m0 - bf2f(hb0)), lb1 = f2bf(m1 - bf2f(hb1));
        hv[t] = (uint_t)hb0 | ((uint_t)hb1 << 16);
        lv[t] = (uint_t)lb0 | ((uint_t)lb1 << 16);
    }
    *(uint4*)(oh + (size_t)node * DIM + ch * 8) = make_uint4(hv[0], hv[1], hv[2], hv[3]);
    *(uint4*)(ol + (size_t)node * DIM + ch * 8) = make_uint4(lv[0], lv[1], lv[2], lv[3]);
}

// ---------------- split-bf16 MFMA GEMM ----------------
// out_hi = bf16( relu( mean @ Wl + x @ Wr + bias ) )
// phase0 (mean): A pair -> Ah@Bh + Ah@Bl + Al@Bh
// phase1 (self): A hi (+ lo iff axl_valid) -> Ah@Bh + Ah@Bl (+ Al@Bh)
// LDS k-chunk-major: wave w stages k-chunk w; frag reads 2-way bank aliased.
__global__ __launch_bounds__(256) void mfma_sage_gemm(
    const ushort_t* __restrict__ Amh, const ushort_t* __restrict__ Aml,
    const ushort_t* __restrict__ Axh, const ushort_t* __restrict__ Axl,
    const ushort_t* __restrict__ Blh, const ushort_t* __restrict__ Bll,
    const ushort_t* __restrict__ Brh, const ushort_t* __restrict__ Brl,
    const float* __restrict__ bias, ushort_t* __restrict__ Oh,
    int M, int K, int N, int axl_valid)
{
    __shared__ ushort_t As_h[4096];   // [kc 0..3][row 0..127][8]
    __shared__ ushort_t As_l[4096];
    __shared__ ushort_t Bs_h[4096];
    __shared__ ushort_t Bs_l[4096];

    const int tid  = threadIdx.x;
    const int lane = tid & 63;
    const int wave = tid >> 6;        // = staged k-chunk
    const int wm = (wave & 1) * 64;
    const int wn = (wave >> 1) * 64;
    const int l15 = lane & 15;
    const int quad = lane >> 4;
    const int bm = blockIdx.x * 128;
    const int bn = blockIdx.y * 128;

    // staging LDS dests (ushort offsets): wave-uniform base + lane*8
    const int s0 = wave * 1024 + lane * 8;
    const int s1 = s0 + 512;
    // staging global offsets (ushort offsets, before +k0)
    const size_t gA0 = (size_t)(bm + lane) * K + wave * 8;
    const size_t gA1 = gA0 + (size_t)64 * K;
    const size_t gB0 = (size_t)(bn + lane) * K + wave * 8;
    const size_t gB1 = gB0 + (size_t)64 * K;

    f32x4 acc[4][4];
#pragma unroll
    for (int i = 0; i < 4; ++i)
#pragma unroll
        for (int j = 0; j < 4; ++j) acc[i][j] = (f32x4){0.f, 0.f, 0.f, 0.f};

    for (int phase = 0; phase < 2; ++phase) {
        const ushort_t* __restrict__ Ah = phase ? Axh : Amh;
        const ushort_t* __restrict__ Al = phase ? Axl : Aml;
        const ushort_t* __restrict__ Bh = phase ? Brh : Blh;
        const ushort_t* __restrict__ Bl = phase ? Brl : Bll;
        const bool doAl = (phase == 0) || (axl_valid != 0);
        for (int k0 = 0; k0 < K; k0 += 32) {
            __syncthreads();   // protect LDS reuse
            async_ld16(Ah + gA0 + k0, &As_h[s0]);
            async_ld16(Ah + gA1 + k0, &As_h[s1]);
            if (doAl) {
                async_ld16(Al + gA0 + k0, &As_l[s0]);
                async_ld16(Al + gA1 + k0, &As_l[s1]);
            }
            async_ld16(Bh + gB0 + k0, &Bs_h[s0]);
            async_ld16(Bh + gB1 + k0, &Bs_h[s1]);
            async_ld16(Bl + gB0 + k0, &Bs_l[s0]);
            async_ld16(Bl + gB1 + k0, &Bs_l[s1]);
            __syncthreads();   // drains vmcnt (global_load_lds)

            short8 fah[4], fal[4], fbh[4], fbl[4];
#pragma unroll
            for (int i = 0; i < 4; ++i) {
                const int aoff = quad * 1024 + (wm + i * 16 + l15) * 8;
                const int boff = quad * 1024 + (wn + i * 16 + l15) * 8;
                fah[i] = *(const short8*)&As_h[aoff];
                fbh[i] = *(const short8*)&Bs_h[boff];
                fbl[i] = *(const short8*)&Bs_l[boff];
                if (doAl) fal[i] = *(const short8*)&As_l[aoff];
            }
#pragma unroll
            for (int i = 0; i < 4; ++i)
#pragma unroll
                for (int j = 0; j < 4; ++j) {
                    acc[i][j] = __builtin_amdgcn_mfma_f32_16x16x32_bf16(fah[i], fbh[j], acc[i][j], 0, 0, 0);
                    acc[i][j] = __builtin_amdgcn_mfma_f32_16x16x32_bf16(fah[i], fbl[j], acc[i][j], 0, 0, 0);
                    if (doAl)
                        acc[i][j] = __builtin_amdgcn_mfma_f32_16x16x32_bf16(fal[i], fbh[j], acc[i][j], 0, 0, 0);
                }
        }
    }

    // epilogue: bias + relu + hi-only bf16 store
#pragma unroll
    for (int i = 0; i < 4; ++i) {
        const int row0 = bm + wm + i * 16 + quad * 4;
#pragma unroll
        for (int j = 0; j < 4; ++j) {
            const int col = bn + wn + j * 16 + l15;
            const float bv = bias[col];
#pragma unroll
            for (int r = 0; r < 4; ++r) {
                const int row = row0 + r;
                if (row < M) {
                    float y = fmaxf(acc[i][j][r] + bv, 0.f);
                    Oh[(size_t)row * N + col] = f2bf(y);
                }
            }
        }
    }
}

// ---------------- final FC: reads h3 hi, K=256, N=9 ----------------
__global__ __launch_bounds__(256) void fc_hi_kernel(
    const ushort_t* __restrict__ hh, const float* __restrict__ W,
    const float* __restrict__ b, float* __restrict__ outp, int M)
{
    __shared__ float Ws[256 * N_OUT];
    __shared__ float bs[N_OUT];
    for (int i = threadIdx.x; i < 256 * N_OUT; i += 256) Ws[i] = W[i];
    if (threadIdx.x < N_OUT) bs[threadIdx.x] = b[threadIdx.x];
    __syncthreads();
    const int t = blockIdx.x * 256 + threadIdx.x;
    if (t >= M * N_OUT) return;
    const int i = t / N_OUT;
    const int j = t - i * N_OUT;
    const ushort_t* __restrict__ rh = hh + (size_t)i * 256;
    float s = bs[j];
#pragma unroll 8
    for (int k = 0; k < 256; k += 2) {
        uint_t uh = *(const uint_t*)(rh + k);
        float a0 = __uint_as_float(uh << 16);
        float a1 = __uint_as_float(uh & 0xffff0000u);
        s += a0 * Ws[k * N_OUT + j] + a1 * Ws[(k + 1) * N_OUT + j];
    }
    outp[t] = s;
}

extern "C" void kernel_launch(void* const* d_in, const int* in_sizes, int n_in,
                              void* d_out, int out_size, void* d_ws, size_t ws_size,
                              hipStream_t stream) {
    const float* x   = (const float*)d_in[0];
    const int*   ei  = (const int*)d_in[1];
    const float* Wl1 = (const float*)d_in[2];
    const float* bl1 = (const float*)d_in[3];
    const float* Wr1 = (const float*)d_in[4];
    const float* Wl2 = (const float*)d_in[5];
    const float* bl2 = (const float*)d_in[6];
    const float* Wr2 = (const float*)d_in[7];
    const float* Wl3 = (const float*)d_in[8];
    const float* bl3 = (const float*)d_in[9];
    const float* Wr3 = (const float*)d_in[10];
    const float* Wfc = (const float*)d_in[11];
    const float* bfc = (const float*)d_in[12];
    float* outp = (float*)d_out;

    const int M = in_sizes[0] / N_IN;        // 100000
    const int E = in_sizes[1] / 2;           // 1600000
    const int* src = ei;
    const int* dst = ei + E;
    const int NB = (M + 255) / 256;          // 391 (<512)
    const size_t Mrow = 100352;              // M rounded up, covers gemm OOB rows

    // -------- workspace carve --------
    char* base = (char*)d_ws;
    char* p = base;
    // region0: dead before GEMM3; aliased by h3h
    int*   degi      = (int*)p;   p += Mrow * 4;
    int*   row_start = (int*)p;   p += Mrow * 4;
    int*   partial   = (int*)p;   p += 4096;
    float* invdeg    = (float*)p; p += Mrow * 4;
    int*   colA      = (int*)p;   p += ((size_t)E + 3) / 4 * 16;
    int*   rankb     = (int*)p;   p += ((size_t)E + 3) / 4 * 16;
    ushort_t* xh     = (ushort_t*)p; p += Mrow * 64 * 2;
    ushort_t* xl     = (ushort_t*)p; p += Mrow * 64 * 2;
    ushort_t* h1h    = (ushort_t*)p; p += Mrow * 128 * 2;
    size_t r0_used = (size_t)(p - base);
    size_t h3_need = Mrow * 256 * 2;         // ~51.4 MB (hi-only)
    ushort_t* h3h = (ushort_t*)base;
    p = base + (r0_used > h3_need ? r0_used : h3_need);
    // persistent-through-GEMM3 buffers
    ushort_t* aggh = (ushort_t*)p; p += Mrow * 128 * 2;
    ushort_t* aggl = (ushort_t*)p; p += Mrow * 128 * 2;
    ushort_t* h2h  = (ushort_t*)p; p += Mrow * 128 * 2;
    ushort_t* w1lh = (ushort_t*)p; p += 64 * 128 * 2;
    ushort_t* w1ll = (ushort_t*)p; p += 64 * 128 * 2;
    ushort_t* w1rh = (ushort_t*)p; p += 64 * 128 * 2;
    ushort_t* w1rl = (ushort_t*)p; p += 64 * 128 * 2;
    ushort_t* w2lh = (ushort_t*)p; p += 128 * 128 * 2;
    ushort_t* w2ll = (ushort_t*)p; p += 128 * 128 * 2;
    ushort_t* w2rh = (ushort_t*)p; p += 128 * 128 * 2;
    ushort_t* w2rl = (ushort_t*)p; p += 128 * 128 * 2;
    ushort_t* w3lh = (ushort_t*)p; p += 128 * 256 * 2;
    ushort_t* w3ll = (ushort_t*)p; p += 128 * 256 * 2;
    ushort_t* w3rh = (ushort_t*)p; p += 128 * 256 * 2;
    ushort_t* w3rl = (ushort_t*)p; p += 128 * 256 * 2;
    (void)ws_size; (void)n_in; (void)out_size;

    const int blk = 256;
    const int grid_m = (M + 127) / 128;      // 782

    // -------- CSR build --------
    hipMemsetAsync(degi, 0, Mrow * 4, stream);
    rank_kernel<<<(E + blk - 1) / blk, blk, 0, stream>>>(dst, degi, rankb, E);
    block_sum_kernel<<<NB, blk, 0, stream>>>(degi, partial, M);
    top_scan_par<<<1, 512, 0, stream>>>(partial, NB);
    apply_scan_kernel<<<NB, blk, 0, stream>>>(degi, partial, row_start, invdeg, M);
    fill_kernel<<<(E + blk - 1) / blk, blk, 0, stream>>>(src, dst, row_start, rankb, colA, E);

    // -------- splits --------
    split_kernel<<<((M * 64) + blk - 1) / blk, blk, 0, stream>>>(x, xh, xl, M * 64);
    wsplit_kernel<<<(64 * 128 + blk - 1) / blk, blk, 0, stream>>>(Wl1, w1lh, w1ll, 64, 128);
    wsplit_kernel<<<(64 * 128 + blk - 1) / blk, blk, 0, stream>>>(Wr1, w1rh, w1rl, 64, 128);
    wsplit_kernel<<<(128 * 128 + blk - 1) / blk, blk, 0, stream>>>(Wl2, w2lh, w2ll, 128, 128);
    wsplit_kernel<<<(128 * 128 + blk - 1) / blk, blk, 0, stream>>>(Wr2, w2rh, w2rl, 128, 128);
    wsplit_kernel<<<(128 * 256 + blk - 1) / blk, blk, 0, stream>>>(Wl3, w3lh, w3ll, 128, 256);
    wsplit_kernel<<<(128 * 256 + blk - 1) / blk, blk, 0, stream>>>(Wr3, w3rh, w3rl, 128, 256);

    // -------- layer 1: 64 -> 128 (self term x pair) --------
    gather_mean_hi<8><<<(M + 31) / 32, blk, 0, stream>>>(
        xh, colA, row_start, degi, invdeg, aggh, aggl, M);
    mfma_sage_gemm<<<dim3(grid_m, 1), blk, 0, stream>>>(
        aggh, aggl, xh, xl, w1lh, w1ll, w1rh, w1rl, bl1, h1h, M, 64, 128, 1);

    // -------- layer 2: 128 -> 128 (self term h1 hi-only) --------
    gather_mean_hi<16><<<(M + 15) / 16, blk, 0, stream>>>(
        h1h, colA, row_start, degi, invdeg, aggh, aggl, M);
    mfma_sage_gemm<<<dim3(grid_m, 1), blk, 0, stream>>>(
        aggh, aggl, h1h, (const ushort_t*)nullptr, w2lh, w2ll, w2rh, w2rl, bl2, h2h, M, 128, 128, 0);

    // -------- layer 3: 128 -> 256 (h3h overwrites region0) --------
    gather_mean_hi<16><<<(M + 15) / 16, blk, 0, stream>>>(
        h2h, colA, row_start, degi, invdeg, aggh, aggl, M);
    mfma_sage_gemm<<<dim3(grid_m, 2), blk, 0, stream>>>(
        aggh, aggl, h2h, (const ushort_t*)nullptr, w3lh, w3ll, w3rh, w3rl, bl3, h3h, M, 128, 256, 0);

    // -------- final FC --------
    fc_hi_kernel<<<(M * N_OUT + blk - 1) / blk, blk, 0, stream>>>(
        h3h, Wfc, bfc, outp, M);
}